// Round 9
// baseline (324.443 us; speedup 1.0000x reference)
//
#include <hip/hip_runtime.h>

#define BB 32
#define IDF 64
#define QL 16384
#define CDF 768
#define SL 18
#define SLP 20             // padded row stride for sT rows
#define CLP 21             // odd stride for ctx_l -> conflict-free b32 reads
#define ADIM 100

// ---------------- Kernel A: sT[b,i,s] = sum_c wic[i,c] * ctx[b,c,s]; out init.
// grid = 512 (b = blk>>4, g = blk&15), block = 256 (4 waves, wave = row i).
// ctx[b] staged in LDS once per block: ctx traffic 113 -> 28 MB.
__global__ __launch_bounds__(256, 2) void kA_source(
        const float* __restrict__ ctx,      // [B, CDF, SL]
        const float* __restrict__ wic,      // [IDF, CDF]
        const float* __restrict__ fc_b,     // [ADIM]
        float* __restrict__ sT,             // ws: [B, IDF, SLP]
        float* __restrict__ out)            // [B, ADIM]
{
    __shared__ float ctx_l[CDF * CLP];     // 64512 B (<64 KB static cap)
    const int blk  = blockIdx.x;
    const int tid  = threadIdx.x;
    const int wave = tid >> 6;
    const int lane = tid & 63;
    const int b = blk >> 4;
    const int g = blk & 15;

    // fused out-init (harness poisons out every launch); kB atomics add onto it
    if (blk < 13) {
        const int t = blk * 256 + tid;
        if (t < BB * ADIM) out[t] = fc_b[t % ADIM];
    }

    const float* ctxb = ctx + (size_t)b * CDF * SL;
    for (int t = tid; t < CDF * SL; t += 256) {
        const int c = t / SL;
        const int s = t - c * SL;
        ctx_l[c * CLP + s] = ctxb[t];
    }
    __syncthreads();

    const int i = g * 4 + wave;
    const float* wrow = wic + (size_t)i * CDF;

    float acc[SL];
#pragma unroll
    for (int s = 0; s < SL; s++) acc[s] = 0.f;

#pragma unroll 2
    for (int k = 0; k < CDF / 64; k++) {
        const int c = k * 64 + lane;
        const float wv = wrow[c];                    // coalesced 256 B/wave
#pragma unroll
        for (int s = 0; s < SL; s++) acc[s] += wv * ctx_l[c * CLP + s];  // odd stride: conflict-free
    }
#pragma unroll
    for (int s = 0; s < SL; s++) {
        float a = acc[s];
#pragma unroll
        for (int off = 32; off; off >>= 1) a += __shfl_xor(a, off, 64);
        if (lane == 0) sT[((size_t)b * IDF + i) * SLP + s] = a;
    }
}

// ---------------- Kernel B: attn softmax + fc contraction, 4 b per block.
// grid = (32 qt, 8 bg), block = 512 (8 waves). Phase 2: four sequential
// single-b passes (1 q/thread, depth-8 scalar prefetch, tiny reg footprint).
// Phase 3: fc_w tile read ONCE per 4 b's -> fc_w traffic 200 -> 50 MB.
__global__ __launch_bounds__(512, 2) void kB_attn_fc(
        const float* __restrict__ inp,     // [B, IDF, QL]
        const float* __restrict__ sT,      // [B, IDF, SLP]
        const float* __restrict__ conv_w,  // [IDF]
        const float* __restrict__ conv_b,  // [1]
        const float* __restrict__ fcw,     // [ADIM, QL]
        float* __restrict__ out)           // [B, ADIM]
{
    __shared__ __align__(16) float st_l[4][IDF * SLP];   // 20480 B
    __shared__ __align__(16) float wq_l[4][512];         // 8192 B
    __shared__ float cw_l[IDF];
    __shared__ float v_l[4][SL];
    const int qt  = blockIdx.x;            // 0..31, 512 q each
    const int bg  = blockIdx.y;            // 0..7, 4 b each
    const int tid = threadIdx.x;           // 0..511
    const int wave = tid >> 6;
    const int lane = tid & 63;

    for (int t = tid; t < 4 * IDF * SLP; t += 512) {
        const int bb = t / (IDF * SLP);
        const int r  = t - bb * (IDF * SLP);
        st_l[bb][r] = sT[((size_t)(bg * 4 + bb) * IDF * SLP) + r];
    }
    if (tid < IDF) cw_l[tid] = conv_w[tid];
    __syncthreads();
    if (tid < 4 * SL) {
        const int bb = tid / SL;
        const int s  = tid - bb * SL;
        float a = 0.f;
#pragma unroll
        for (int i = 0; i < IDF; i++) a += cw_l[i] * st_l[bb][i * SLP + s];
        v_l[bb][s] = a;
    }
    __syncthreads();

    // ---- Phase 2: per b-pass, 1 q per thread
    const int q = qt * 512 + tid;
    const float cb = conv_b[0];

#pragma unroll 1
    for (int bb = 0; bb < 4; bb++) {
        const float* ip = inp + ((size_t)(bg * 4 + bb) * IDF) * QL + q;

        float xa[8];
#pragma unroll
        for (int j = 0; j < 8; j++) xa[j] = ip[(size_t)j * QL];

        float sc[SL];
#pragma unroll
        for (int s = 0; s < SL; s++) sc[s] = 0.f;

#pragma unroll 8
        for (int i = 0; i < IDF; i++) {
            const float x = xa[i & 7];
            if (i + 8 < IDF) xa[i & 7] = ip[(size_t)(i + 8) * QL];
            float r[SLP];
            const float4* r4 = (const float4*)&st_l[bb][i * SLP];  // wave-uniform broadcast
            ((float4*)r)[0] = r4[0];
            ((float4*)r)[1] = r4[1];
            ((float4*)r)[2] = r4[2];
            ((float4*)r)[3] = r4[3];
            ((float2*)(r + 16))[0] = *(const float2*)&st_l[bb][i * SLP + 16];
#pragma unroll
            for (int s = 0; s < SL; s++) sc[s] += x * r[s];
        }

        float m = sc[0];
#pragma unroll
        for (int s = 1; s < SL; s++) m = fmaxf(m, sc[s]);
        float l = 0.f, o = 0.f;
#pragma unroll
        for (int s = 0; s < SL; s++) {
            const float p = __expf(sc[s] - m);
            l += p;
            o += p * v_l[bb][s];
        }
        wq_l[bb][tid] = o / l + cb;
    }
    __syncthreads();

    // ---- Phase 3: wave w handles a in {w, w+8, ...}; fcw tile read once for 4 b.
    float wv[4][8];
#pragma unroll
    for (int bb = 0; bb < 4; bb++) {
        ((float4*)wv[bb])[0] = *(const float4*)&wq_l[bb][lane * 8];
        ((float4*)wv[bb])[1] = *(const float4*)&wq_l[bb][lane * 8 + 4];
    }

    const float* fcw_t = fcw + (size_t)qt * 512 + lane * 8;
#pragma unroll 1
    for (int a = wave; a < ADIM; a += 8) {
        const float* fr = fcw_t + (size_t)a * QL;
        const float4 f0 = *(const float4*)fr;
        const float4 f1 = *(const float4*)(fr + 4);
        float f[8];
        ((float4*)f)[0] = f0;
        ((float4*)f)[1] = f1;
#pragma unroll
        for (int bb = 0; bb < 4; bb++) {
            float acc = 0.f;
#pragma unroll
            for (int j = 0; j < 8; j++) acc += f[j] * wv[bb][j];
#pragma unroll
            for (int off = 32; off; off >>= 1) acc += __shfl_xor(acc, off, 64);
            if (lane == 0) atomicAdd(&out[(bg * 4 + bb) * ADIM + a], acc);
        }
    }
}

extern "C" void kernel_launch(void* const* d_in, const int* in_sizes, int n_in,
                              void* d_out, int out_size, void* d_ws, size_t ws_size,
                              hipStream_t stream)
{
    const float* inputs     = (const float*)d_in[0];  // [32,64,128,128]
    const float* context    = (const float*)d_in[1];  // [32,768,18]
    const float* conv_ctx_w = (const float*)d_in[2];  // [64,768]
    const float* conv_w     = (const float*)d_in[3];  // [64]
    const float* conv_b     = (const float*)d_in[4];  // [1]
    const float* fc_w       = (const float*)d_in[5];  // [100,16384]
    const float* fc_b       = (const float*)d_in[6];  // [100]
    float* out = (float*)d_out;

    float* ws = (float*)d_ws;
    float* sT = ws;                                   // 32*64*20 = 40960 floats

    kA_source<<<dim3(512), dim3(256), 0, stream>>>(context, conv_ctx_w, fc_b, sT, out);
    kB_attn_fc<<<dim3(32, 8), dim3(512), 0, stream>>>(inputs, sT, conv_w, conv_b, fc_w, out);
}

// Round 10
// 238.264 us; speedup vs baseline: 1.3617x; 1.3617x over previous
//
#include <hip/hip_runtime.h>

#define BB 32
#define IDF 64
#define QL 16384
#define CDF 768
#define SL 18
#define SLP 20             // padded row stride for sT rows
#define CLP 21             // odd stride for ctx_l -> conflict-free b32 reads
#define ADIM 100

// ---------------- Kernel A: sT[b,i,s] = sum_c wic[i,c] * ctx[b,c,s]; out init.
// grid = 512 (b = blk>>4, g = blk&15), block = 256 (4 waves, wave = row i).
// ctx[b] staged in LDS once per block: ctx traffic 113 -> 28 MB.
__global__ __launch_bounds__(256, 2) void kA_source(
        const float* __restrict__ ctx,      // [B, CDF, SL]
        const float* __restrict__ wic,      // [IDF, CDF]
        const float* __restrict__ fc_b,     // [ADIM]
        float* __restrict__ sT,             // ws: [B, IDF, SLP]
        float* __restrict__ out)            // [B, ADIM]
{
    __shared__ float ctx_l[CDF * CLP];     // 64512 B
    const int blk  = blockIdx.x;
    const int tid  = threadIdx.x;
    const int wave = tid >> 6;
    const int lane = tid & 63;
    const int b = blk >> 4;
    const int g = blk & 15;

    // fused out-init (harness poisons out every launch); kC atomics add onto it
    if (blk < 13) {
        const int t = blk * 256 + tid;
        if (t < BB * ADIM) out[t] = fc_b[t % ADIM];
    }

    const float* ctxb = ctx + (size_t)b * CDF * SL;
    for (int t = tid; t < CDF * SL; t += 256) {
        const int c = t / SL;
        const int s = t - c * SL;
        ctx_l[c * CLP + s] = ctxb[t];
    }
    __syncthreads();

    const int i = g * 4 + wave;
    const float* wrow = wic + (size_t)i * CDF;

    float acc[SL];
#pragma unroll
    for (int s = 0; s < SL; s++) acc[s] = 0.f;

#pragma unroll 2
    for (int k = 0; k < CDF / 64; k++) {
        const int c = k * 64 + lane;
        const float wv = wrow[c];                    // coalesced 256 B/wave
#pragma unroll
        for (int s = 0; s < SL; s++) acc[s] += wv * ctx_l[c * CLP + s];  // odd stride: 2-way max
    }
#pragma unroll
    for (int s = 0; s < SL; s++) {
        float a = acc[s];
#pragma unroll
        for (int off = 32; off; off >>= 1) a += __shfl_xor(a, off, 64);
        if (lane == 0) sT[((size_t)b * IDF + i) * SLP + s] = a;
    }
}

// ---------------- Kernel B: scores -> softmax -> dot(v) -> wq (global).
// EXACT R8 phase-2 structure (measured 80 us fused; predict ~35-40 standalone).
// grid = (32 qt, 32 b), block 256, 2 q/thread (float2), 4-deep rolling prefetch.
__global__ __launch_bounds__(256, 2) void kB_attn(
        const float* __restrict__ inp,     // [B, IDF, QL]
        const float* __restrict__ sT,      // [B, IDF, SLP]
        const float* __restrict__ conv_w,  // [IDF]
        const float* __restrict__ conv_b,  // [1]
        float* __restrict__ wq)            // ws: [B, QL]
{
    __shared__ __align__(16) float st_l[IDF * SLP];   // 5120 B
    __shared__ float cw_l[IDF];
    __shared__ float v_l[SL];
    const int b   = blockIdx.y;
    const int qt  = blockIdx.x;
    const int tid = threadIdx.x;

    for (int t = tid; t < IDF * SLP; t += 256) st_l[t] = sT[(size_t)b * IDF * SLP + t];
    if (tid < IDF) cw_l[tid] = conv_w[tid];
    __syncthreads();
    if (tid < SL) {
        float a = 0.f;
#pragma unroll
        for (int i = 0; i < IDF; i++) a += cw_l[i] * st_l[i * SLP + tid];
        v_l[tid] = a;
    }
    __syncthreads();

    const float2* ip2 = (const float2*)(inp + (size_t)b * IDF * QL + (size_t)qt * 512);

    float2 sc[SL];
#pragma unroll
    for (int s = 0; s < SL; s++) sc[s] = make_float2(0.f, 0.f);

    float2 xb[4];
#pragma unroll
    for (int j = 0; j < 4; j++) xb[j] = ip2[(size_t)j * (QL / 2) + tid];

#pragma unroll 4
    for (int i = 0; i < IDF; i++) {
        const float2 x = xb[i & 3];
        if (i + 4 < IDF) xb[i & 3] = ip2[(size_t)(i + 4) * (QL / 2) + tid];
        float r[SL];
        const float4* r4 = (const float4*)&st_l[i * SLP];  // wave-uniform -> broadcast
        ((float4*)r)[0] = r4[0];
        ((float4*)r)[1] = r4[1];
        ((float4*)r)[2] = r4[2];
        ((float4*)r)[3] = r4[3];
        ((float2*)(r + 16))[0] = *(const float2*)&st_l[i * SLP + 16];
#pragma unroll
        for (int s = 0; s < SL; s++) {
            sc[s].x += x.x * r[s];
            sc[s].y += x.y * r[s];
        }
    }

    float2 m = sc[0];
#pragma unroll
    for (int s = 1; s < SL; s++) {
        m.x = fmaxf(m.x, sc[s].x);
        m.y = fmaxf(m.y, sc[s].y);
    }
    float2 l = make_float2(0.f, 0.f);
    float2 o = make_float2(0.f, 0.f);
#pragma unroll
    for (int s = 0; s < SL; s++) {
        const float vs = v_l[s];
        float2 p;
        p.x = __expf(sc[s].x - m.x);
        p.y = __expf(sc[s].y - m.y);
        l.x += p.x; l.y += p.y;
        o.x += p.x * vs; o.y += p.y * vs;
    }
    const float cb = conv_b[0];
    float2 res;
    res.x = o.x / l.x + cb;
    res.y = o.y / l.y + cb;
    ((float2*)(wq + (size_t)b * QL + (size_t)qt * 512))[tid] = res;
}

// ---------------- Kernel C: out[b,a] += sum_q wq[b,q] * fcw[a,q]
// grid = 320 = 4 bg(8 b) x 10 ag(10 a) x 8 qc(2048 q); block = 320 (5 waves).
// Wave = 2a x 8b register tile over its 2048-q chunk. Unique traffic:
// fc_w x4 (25 MB) + wq x10 (20 MB); intra-block re-reads hit L1/L2.
__global__ __launch_bounds__(320, 2) void kC_fc(
        const float* __restrict__ wq,      // [B, QL]
        const float* __restrict__ fcw,     // [ADIM, QL]
        float* __restrict__ out)           // [B, ADIM]
{
    const int blk = blockIdx.x;
    const int bg  = blk / 80;              // 0..3
    const int rem = blk - bg * 80;
    const int ag  = rem >> 3;              // 0..9
    const int qc  = rem & 7;               // 0..7
    const int wave = threadIdx.x >> 6;     // 0..4
    const int lane = threadIdx.x & 63;
    const int a0 = ag * 10 + wave * 2;
    const int b0 = bg * 8;
    const int q0 = qc * 2048;

    float acc[2][8];
#pragma unroll
    for (int j = 0; j < 2; j++)
#pragma unroll
        for (int i = 0; i < 8; i++) acc[j][i] = 0.f;

#pragma unroll 2
    for (int k = 0; k < 8; k++) {
        const int qi = q0 + (k * 64 + lane) * 4;
        float4 fv[2];
#pragma unroll
        for (int j = 0; j < 2; j++) fv[j] = *(const float4*)(fcw + (size_t)(a0 + j) * QL + qi);
        float4 wv[8];
#pragma unroll
        for (int i = 0; i < 8; i++) wv[i] = *(const float4*)(wq + (size_t)(b0 + i) * QL + qi);
#pragma unroll
        for (int j = 0; j < 2; j++)
#pragma unroll
            for (int i = 0; i < 8; i++)
                acc[j][i] += fv[j].x * wv[i].x + fv[j].y * wv[i].y
                           + fv[j].z * wv[i].z + fv[j].w * wv[i].w;
    }

#pragma unroll
    for (int j = 0; j < 2; j++) {
#pragma unroll
        for (int i = 0; i < 8; i++) {
            float r = acc[j][i];
#pragma unroll
            for (int off = 32; off; off >>= 1) r += __shfl_xor(r, off, 64);
            if (lane == 0) atomicAdd(&out[(b0 + i) * ADIM + a0 + j], r);
        }
    }
}

extern "C" void kernel_launch(void* const* d_in, const int* in_sizes, int n_in,
                              void* d_out, int out_size, void* d_ws, size_t ws_size,
                              hipStream_t stream)
{
    const float* inputs     = (const float*)d_in[0];  // [32,64,128,128]
    const float* context    = (const float*)d_in[1];  // [32,768,18]
    const float* conv_ctx_w = (const float*)d_in[2];  // [64,768]
    const float* conv_w     = (const float*)d_in[3];  // [64]
    const float* conv_b     = (const float*)d_in[4];  // [1]
    const float* fc_w       = (const float*)d_in[5];  // [100,16384]
    const float* fc_b       = (const float*)d_in[6];  // [100]
    float* out = (float*)d_out;

    float* ws = (float*)d_ws;
    float* sT = ws;                                   // 32*64*20 = 40960 floats
    float* wq = ws + (size_t)BB * IDF * SLP;          // 524288 floats

    kA_source<<<dim3(512), dim3(256), 0, stream>>>(context, conv_ctx_w, fc_b, sT, out);
    kB_attn<<<dim3(32, BB), dim3(256), 0, stream>>>(inputs, sT, conv_w, conv_b, wq);
    kC_fc<<<dim3(320), dim3(320), 0, stream>>>(wq, fc_w, out);
}